// Round 6
// baseline (212.465 us; speedup 1.0000x reference)
//
#include <hip/hip_runtime.h>
#include <hip/hip_bf16.h>

#define BB 8
#define CC 128
#define HH 64
#define WW 64
#define OO 128
#define NJ 18
#define HW 4096
#define KDIM 1152

typedef unsigned short u16;
typedef unsigned int u32;
typedef __attribute__((ext_vector_type(8))) __bf16 bf16x8;
typedef __attribute__((ext_vector_type(4))) float f32x4;

__device__ __forceinline__ u16 f2bf(float f) {
    u32 u = __float_as_uint(f);
    u += 0x7fffu + ((u >> 16) & 1u);   // RNE
    return (u16)(u >> 16);
}
__device__ __forceinline__ float bflo(u32 u) { return __uint_as_float(u << 16); }
__device__ __forceinline__ float bfhi(u32 u) { return __uint_as_float(u & 0xffff0000u); }
__device__ __forceinline__ u32 pk2bf(float s0, float s1) {
    union { __hip_bfloat162 h; u32 u; } cv;
    cv.h = __float22bfloat162_rn(make_float2(s0, s1));   // v_cvt_pk_bf16_f32
    return cv.u;
}

// ---------------------------------------------------------------------------
// k_pre: fused (a) x[b][c][hw] fp32 -> xT[b][hw][c] bf16 transpose and
//        (b) weight prep (wT, wA). Blocks [0,512) do xT, [512,1088) do prep.
// ---------------------------------------------------------------------------
__global__ __launch_bounds__(256)
void k_pre(const float* __restrict__ x, u16* __restrict__ xT,
           const float* __restrict__ w_def, const float* __restrict__ w_off,
           u16* __restrict__ wT, u16* __restrict__ wA) {
    __shared__ float tile[64][129];
    const int t = threadIdx.x;
    if (blockIdx.x < 512) {
        const int b = blockIdx.x >> 6;
        const int hw0 = (blockIdx.x & 63) << 6;
        const float* xb = x + (size_t)b * CC * HW + hw0;
        const int tw = t & 63, tc = t >> 6;
#pragma unroll
        for (int r = 0; r < 32; ++r) {
            int c = r * 4 + tc;                 // wave-uniform
            tile[tw][c] = xb[c * HW + tw];
        }
        __syncthreads();
        u16* dst = xT + ((size_t)b * HW + hw0) * CC;
#pragma unroll
        for (int r = 0; r < 4; ++r) {
            int item = t + (r << 8);            // 1024 items = 64 hw x 16 segs
            int seg = item & 15, hw = item >> 4;
            union { u32 d[4]; uint4 v; } p;
#pragma unroll
            for (int i = 0; i < 4; ++i)
                p.d[i] = pk2bf(tile[hw][seg * 8 + 2 * i], tile[hw][seg * 8 + 2 * i + 1]);
            *(uint4*)&dst[hw * CC + seg * 8] = p.v;
        }
    } else {
        int idx = (blockIdx.x - 512) * 256 + t;
        if (idx < 9 * OO * CC) {
            int c = idx & 127, o = (idx >> 7) & 127, kk = idx >> 14;
            wT[idx] = f2bf(w_def[(o * CC + c) * 9 + kk]);
        }
        if (idx < 32 * 1152) {
            int k = idx % 1152, j = idx / 1152;
            int q = k >> 7, c = k & 127;
            wA[idx] = (j < NJ) ? f2bf(w_off[(j * CC + c) * 9 + q]) : (u16)0;
        }
    }
}

// ---------------------------------------------------------------------------
// k_off: offset conv via MFMA, M=18(->32), N=64, K=1152. Round-0 verbatim
// (proven correct & fast as a standalone kernel).
// ---------------------------------------------------------------------------
__global__ __launch_bounds__(256, 2)
void k_off(const u16* __restrict__ xT, const u16* __restrict__ wA,
           const float* __restrict__ b_off, float* __restrict__ offs) {
    __shared__ u16 s_x[198 * 128];   // [3 rows x 66 w][128 c] swizzled
    const int t = threadIdx.x, lane = t & 63, wv = t >> 6;
    const int posl = lane & 15, kg = lane >> 4;
    const int b = blockIdx.x & 7, h = blockIdx.x >> 3;

    for (int it = t; it < 3168; it += 256) {
        int seg = it & 15, pix = it >> 4;       // pix = r*66 + wp
        int r = pix / 66, wp = pix - r * 66;
        int y = h - 1 + r, w = wp - 1;
        uint4 v = make_uint4(0, 0, 0, 0);
        if (y >= 0 && y < HH && w >= 0 && w < WW)
            v = *(const uint4*)&xT[((size_t)(b * HW) + y * WW + w) * CC + seg * 8];
        *(uint4*)&s_x[pix * 128 + ((seg ^ (pix & 15)) * 8)] = v;
    }
    __syncthreads();

    f32x4 acc0 = {0.f, 0.f, 0.f, 0.f}, acc1 = {0.f, 0.f, 0.f, 0.f};
    for (int q = 0; q < 9; ++q) {
        int qy = q / 3, qx = q - qy * 3;
        int pix = qy * 66 + (wv * 16 + posl) + qx;
        int prow = pix * 128, pxor = pix & 15;
#pragma unroll
        for (int ki = 0; ki < 4; ++ki) {
            int ks = q * 4 + ki;
            int cidx = ki * 4 + kg;
            bf16x8 bfr = *(const bf16x8*)&s_x[prow + ((cidx ^ pxor) * 8)];
            bf16x8 a0 = *(const bf16x8*)&wA[posl * 1152 + ks * 32 + kg * 8];
            bf16x8 a1 = *(const bf16x8*)&wA[(16 + posl) * 1152 + ks * 32 + kg * 8];
            acc0 = __builtin_amdgcn_mfma_f32_16x16x32_bf16(a0, bfr, acc0, 0, 0, 0);
            acc1 = __builtin_amdgcn_mfma_f32_16x16x32_bf16(a1, bfr, acc1, 0, 0, 0);
        }
    }
    const int pos = wv * 16 + posl;
#pragma unroll
    for (int r = 0; r < 4; ++r) {
        int j = kg * 4 + r;
        offs[(b * NJ + j) * HW + h * WW + pos] = acc0[r] + b_off[j];
    }
#pragma unroll
    for (int r = 0; r < 4; ++r) {
        int j = 16 + kg * 4 + r;
        if (j < NJ) offs[(b * NJ + j) * HW + h * WW + pos] = acc1[r] + b_off[j];
    }
}

// ---------------------------------------------------------------------------
// k_samp: gather + bilinear interp -> sampT[b][pos][kk*128+c] bf16.
// NO LDS, NO barriers. Grid = 512 (b,h) x 3 kk-groups = 1536 blocks -> up to
// 6 blocks/CU co-resident (24 waves/CU); pure TLP hides gather latency.
// Gather/interp lambdas verbatim from the proven round-1 kernel; only the
// store target changed (LDS s_samp -> global sampT, unswizzled).
// ---------------------------------------------------------------------------
__global__ __launch_bounds__(256, 4)
void k_samp(const u16* __restrict__ xT, const float* __restrict__ offs,
            u16* __restrict__ sampT) {
    const int t = threadIdx.x;
    const int bid = blockIdx.x;
    const int kkg = bid % 3;                 // kk in {kkg*3 .. kkg*3+2}
    const int bh = bid / 3;
    const int b = bh >> 6, h = bh & 63;
    const char* xb = (const char*)xT + (size_t)b * (HW * CC * 2);

    const int gpos = t >> 2;                 // 0..63 (= w)
    const int segsub = t & 3;

    u16* srow = sampT + ((size_t)(b * HW) + h * WW + gpos) * KDIM;

    // preload this group's 6 offset values
    float oyv[3], oxv[3];
#pragma unroll
    for (int i = 0; i < 3; ++i) {
        int kk = kkg * 3 + i;
        oyv[i] = offs[(b * NJ + 2 * kk) * HW + h * WW + gpos];
        oxv[i] = offs[(b * NJ + 2 * kk + 1) * HW + h * WW + gpos];
    }

    auto coords = [&](int kk, float oy, float ox, float4& cw, int4& co) {
        int ky = kk / 3, kx = kk - ky * 3;
        float py = (float)(h - 1 + ky) + oy;
        float px = (float)(gpos - 1 + kx) + ox;
        float fy = floorf(py), fx = floorf(px);
        int iy0 = (int)fy, ix0 = (int)fx;
        float wy = py - fy, wx = px - fx;
        int iy1 = iy0 + 1, ix1 = ix0 + 1;
        float my0 = (iy0 >= 0 && iy0 < HH) ? 1.0f : 0.0f;
        float my1 = (iy1 >= 0 && iy1 < HH) ? 1.0f : 0.0f;
        float mx0 = (ix0 >= 0 && ix0 < WW) ? 1.0f : 0.0f;
        float mx1 = (ix1 >= 0 && ix1 < WW) ? 1.0f : 0.0f;
        int iy0c = min(max(iy0, 0), HH - 1), iy1c = min(max(iy1, 0), HH - 1);
        int ix0c = min(max(ix0, 0), WW - 1), ix1c = min(max(ix1, 0), WW - 1);
        float wy1 = 1.0f - wy, wx1 = 1.0f - wx;
        cw = make_float4(my0 * mx0 * wy1 * wx1, my0 * mx1 * wy1 * wx,
                         my1 * mx0 * wy  * wx1, my1 * mx1 * wy  * wx);
        co = make_int4((iy0c * WW + ix0c) << 8, (iy0c * WW + ix1c) << 8,
                       (iy1c * WW + ix0c) << 8, (iy1c * WW + ix1c) << 8);
    };
    auto issue_gather = [&](const int4 co, uint4 q[4][4]) {
#pragma unroll
        for (int j = 0; j < 4; ++j) {
            const int sb = (segsub + 4 * j) * 16;
            q[j][0] = *(const uint4*)(xb + co.x + sb);
            q[j][1] = *(const uint4*)(xb + co.y + sb);
            q[j][2] = *(const uint4*)(xb + co.z + sb);
            q[j][3] = *(const uint4*)(xb + co.w + sb);
        }
    };

#pragma unroll
    for (int i = 0; i < 3; ++i) {
        const int kk = kkg * 3 + i;
        float4 cw; int4 co;
        coords(kk, oyv[i], oxv[i], cw, co);
        uint4 q[4][4];
        issue_gather(co, q);
#pragma unroll
        for (int j = 0; j < 4; ++j) {
            const int seg = segsub + 4 * j;
            const u32* u00 = (const u32*)&q[j][0];
            const u32* u01 = (const u32*)&q[j][1];
            const u32* u10 = (const u32*)&q[j][2];
            const u32* u11 = (const u32*)&q[j][3];
            union { u32 d[4]; uint4 v; } pk;
#pragma unroll
            for (int ii = 0; ii < 4; ++ii) {
                float s0 = cw.x * bflo(u00[ii]) + cw.y * bflo(u01[ii])
                         + cw.z * bflo(u10[ii]) + cw.w * bflo(u11[ii]);
                float s1 = cw.x * bfhi(u00[ii]) + cw.y * bfhi(u01[ii])
                         + cw.z * bfhi(u10[ii]) + cw.w * bfhi(u11[ii]);
                pk.d[ii] = pk2bf(s0, s1);
            }
            *(uint4*)&srow[kk * 128 + seg * 8] = pk.v;
        }
    }
}

// ---------------------------------------------------------------------------
// k_gemm: out[b][o][h][w] = sampT[b][pos][:] . wT[kk][o][:] + b_def.
// v5's PROVEN MFMA loop with A[ks] loaded coalesced from sampT instead of
// computed in-thread. NO LDS, NO barriers. o-split: grid = 512 (b,h) x 2
// o-halves = 1024 blocks -> 4 blocks/CU (16 waves/CU); per-wave weight
// traffic halved vs v5. Wave wv owns positions p0=wv*16..+15 x 64 o.
// ---------------------------------------------------------------------------
__global__ __launch_bounds__(256, 4)
void k_gemm(const u16* __restrict__ sampT, const u16* __restrict__ wT,
            const float* __restrict__ b_def, float* __restrict__ out) {
    const int t = threadIdx.x, lane = t & 63, wv = t >> 6;   // wv 0..3
    const int posl = lane & 15, kg = lane >> 4;
    const int bid = blockIdx.x;
    const int oh = bid & 1;                  // o-half
    const int bh = bid >> 1;
    const int b = bh >> 6, h = bh & 63;
    const int p0 = wv * 16;
    const int o0 = oh * 64;

    const u16* arow = sampT + ((size_t)(b * HW) + h * WW + p0 + posl) * KDIM;

    f32x4 acc[4];
#pragma unroll
    for (int ot = 0; ot < 4; ++ot) acc[ot] = (f32x4){0.f, 0.f, 0.f, 0.f};

#pragma unroll
    for (int kk = 0; kk < 9; ++kk) {
        // A-fragments: lane (posl,kg) holds row p0+posl, ch ks*32+kg*8+{0..7}
        bf16x8 A[4];
#pragma unroll
        for (int ks = 0; ks < 4; ++ks)
            A[ks] = *(const bf16x8*)&arow[kk * 128 + ks * 32 + kg * 8];

        const u16* wkk = wT + kk * (OO * CC);
#pragma unroll
        for (int ks = 0; ks < 4; ++ks)
#pragma unroll
            for (int ot = 0; ot < 4; ++ot) {
                bf16x8 wfr = *(const bf16x8*)
                    &wkk[(o0 + ot * 16 + posl) * CC + ks * 32 + kg * 8];
                acc[ot] = __builtin_amdgcn_mfma_f32_16x16x32_bf16(
                    A[ks], wfr, acc[ot], 0, 0, 0);
            }
    }

    // epilogue (v5-verified layout): D col = o, row = pos = p0 + kg*4 + r
#pragma unroll
    for (int ot = 0; ot < 4; ++ot) {
        const int o = o0 + ot * 16 + posl;
        const float bd = b_def[o];
        float4 res;
        res.x = acc[ot][0] + bd;
        res.y = acc[ot][1] + bd;
        res.z = acc[ot][2] + bd;
        res.w = acc[ot][3] + bd;
        *(float4*)&out[((b * OO + o) * HH + h) * WW + p0 + kg * 4] = res;
    }
}

extern "C" void kernel_launch(void* const* d_in, const int* in_sizes, int n_in,
                              void* d_out, int out_size, void* d_ws, size_t ws_size,
                              hipStream_t stream) {
    const float* x     = (const float*)d_in[0];
    const float* w_off = (const float*)d_in[1];
    const float* b_off = (const float*)d_in[2];
    const float* w_def = (const float*)d_in[3];
    const float* b_def = (const float*)d_in[4];
    float* out = (float*)d_out;

    float* offs  = (float*)d_ws;                 // 8*18*4096 f32 = 2.36 MB
    u16*   xT    = (u16*)(offs + BB * NJ * HW);  // 8*4096*128    = 8.39 MB
    u16*   wT    = xT + (size_t)BB * HW * CC;    // 9*128*128     = 0.29 MB
    u16*   wA    = wT + 9 * OO * CC;             // 32*1152       = 0.07 MB
    u16*   sampT = wA + 32 * 1152;               // 8*4096*1152   = 75.5 MB

    k_pre <<<1088, 256, 0, stream>>>(x, xT, w_def, w_off, wT, wA);
    k_off <<< 512, 256, 0, stream>>>(xT, wA, b_off, offs);
    k_samp<<<1536, 256, 0, stream>>>(xT, offs, sampT);
    k_gemm<<<1024, 256, 0, stream>>>(sampT, wT, b_def, out);
}

// Round 8
// 177.785 us; speedup vs baseline: 1.1951x; 1.1951x over previous
//
#include <hip/hip_runtime.h>
#include <hip/hip_bf16.h>

#define BB 8
#define CC 128
#define HH 64
#define WW 64
#define OO 128
#define NJ 18
#define HW 4096

typedef unsigned short u16;
typedef unsigned int u32;
typedef __attribute__((ext_vector_type(8))) __bf16 bf16x8;
typedef __attribute__((ext_vector_type(4))) float f32x4;

__device__ __forceinline__ u16 f2bf(float f) {
    u32 u = __float_as_uint(f);
    u += 0x7fffu + ((u >> 16) & 1u);   // RNE
    return (u16)(u >> 16);
}
__device__ __forceinline__ float bflo(u32 u) { return __uint_as_float(u << 16); }
__device__ __forceinline__ float bfhi(u32 u) { return __uint_as_float(u & 0xffff0000u); }
__device__ __forceinline__ u32 pk2bf(float s0, float s1) {
    union { __hip_bfloat162 h; u32 u; } cv;
    cv.h = __float22bfloat162_rn(make_float2(s0, s1));   // v_cvt_pk_bf16_f32
    return cv.u;
}

// ---------------------------------------------------------------------------
// k_pre: fused (a) x[b][c][hw] fp32 -> xT[b][hw][c] bf16 transpose and
//        (b) weight prep (wT, wA). Blocks [0,512) do xT, [512,1088) do prep.
// ---------------------------------------------------------------------------
__global__ __launch_bounds__(256)
void k_pre(const float* __restrict__ x, u16* __restrict__ xT,
           const float* __restrict__ w_def, const float* __restrict__ w_off,
           u16* __restrict__ wT, u16* __restrict__ wA) {
    __shared__ float tile[64][129];
    const int t = threadIdx.x;
    if (blockIdx.x < 512) {
        const int b = blockIdx.x >> 6;
        const int hw0 = (blockIdx.x & 63) << 6;
        const float* xb = x + (size_t)b * CC * HW + hw0;
        const int tw = t & 63, tc = t >> 6;
#pragma unroll
        for (int r = 0; r < 32; ++r) {
            int c = r * 4 + tc;                 // wave-uniform
            tile[tw][c] = xb[c * HW + tw];
        }
        __syncthreads();
        u16* dst = xT + ((size_t)b * HW + hw0) * CC;
#pragma unroll
        for (int r = 0; r < 4; ++r) {
            int item = t + (r << 8);            // 1024 items = 64 hw x 16 segs
            int seg = item & 15, hw = item >> 4;
            union { u32 d[4]; uint4 v; } p;
#pragma unroll
            for (int i = 0; i < 4; ++i)
                p.d[i] = pk2bf(tile[hw][seg * 8 + 2 * i], tile[hw][seg * 8 + 2 * i + 1]);
            *(uint4*)&dst[hw * CC + seg * 8] = p.v;
        }
    } else {
        int idx = (blockIdx.x - 512) * 256 + t;
        if (idx < 9 * OO * CC) {
            int c = idx & 127, o = (idx >> 7) & 127, kk = idx >> 14;
            wT[idx] = f2bf(w_def[(o * CC + c) * 9 + kk]);
        }
        if (idx < 32 * 1152) {
            int k = idx % 1152, j = idx / 1152;
            int q = k >> 7, c = k & 127;
            wA[idx] = (j < NJ) ? f2bf(w_off[(j * CC + c) * 9 + q]) : (u16)0;
        }
    }
}

// ---------------------------------------------------------------------------
// k_off: offset conv via MFMA, M=18(->32), N=64, K=1152. Round-0 verbatim.
// ---------------------------------------------------------------------------
__global__ __launch_bounds__(256, 2)
void k_off(const u16* __restrict__ xT, const u16* __restrict__ wA,
           const float* __restrict__ b_off, float* __restrict__ offs) {
    __shared__ u16 s_x[198 * 128];   // [3 rows x 66 w][128 c] swizzled
    const int t = threadIdx.x, lane = t & 63, wv = t >> 6;
    const int posl = lane & 15, kg = lane >> 4;
    const int b = blockIdx.x & 7, h = blockIdx.x >> 3;

    for (int it = t; it < 3168; it += 256) {
        int seg = it & 15, pix = it >> 4;       // pix = r*66 + wp
        int r = pix / 66, wp = pix - r * 66;
        int y = h - 1 + r, w = wp - 1;
        uint4 v = make_uint4(0, 0, 0, 0);
        if (y >= 0 && y < HH && w >= 0 && w < WW)
            v = *(const uint4*)&xT[((size_t)(b * HW) + y * WW + w) * CC + seg * 8];
        *(uint4*)&s_x[pix * 128 + ((seg ^ (pix & 15)) * 8)] = v;
    }
    __syncthreads();

    f32x4 acc0 = {0.f, 0.f, 0.f, 0.f}, acc1 = {0.f, 0.f, 0.f, 0.f};
    for (int q = 0; q < 9; ++q) {
        int qy = q / 3, qx = q - qy * 3;
        int pix = qy * 66 + (wv * 16 + posl) + qx;
        int prow = pix * 128, pxor = pix & 15;
#pragma unroll
        for (int ki = 0; ki < 4; ++ki) {
            int ks = q * 4 + ki;
            int cidx = ki * 4 + kg;
            bf16x8 bfr = *(const bf16x8*)&s_x[prow + ((cidx ^ pxor) * 8)];
            bf16x8 a0 = *(const bf16x8*)&wA[posl * 1152 + ks * 32 + kg * 8];
            bf16x8 a1 = *(const bf16x8*)&wA[(16 + posl) * 1152 + ks * 32 + kg * 8];
            acc0 = __builtin_amdgcn_mfma_f32_16x16x32_bf16(a0, bfr, acc0, 0, 0, 0);
            acc1 = __builtin_amdgcn_mfma_f32_16x16x32_bf16(a1, bfr, acc1, 0, 0, 0);
        }
    }
    const int pos = wv * 16 + posl;
#pragma unroll
    for (int r = 0; r < 4; ++r) {
        int j = kg * 4 + r;
        offs[(b * NJ + j) * HW + h * WW + pos] = acc0[r] + b_off[j];
    }
#pragma unroll
    for (int r = 0; r < 4; ++r) {
        int j = 16 + kg * 4 + r;
        if (j < NJ) offs[(b * NJ + j) * HW + h * WW + pos] = acc1[r] + b_off[j];
    }
}

// ---------------------------------------------------------------------------
// k_main v7b: ASYNC-DMA corner pipeline (global_load_lds) + direct-A GEMM.
// Identical schedule to v7 but ALL hand-rolled sync (raw s_barrier + asm
// vmcnt + sched_barrier) replaced with plain __syncthreads(). For THIS
// schedule that is semantically identical: v7 already drained vmcnt(0) at
// each iteration bottom; the pipeline win is the DMA being in flight DURING
// the interp+MFMA phase (~600-800 cyc), which is preserved. Removes the
// hang-risk class entirely (round-7 container death was either infra or
// hand-rolled-sync-induced; this disambiguates).
//
// Block = 256 thr (4 waves), owns (b, h, 32-pos half-row). Grid 1024.
//  - s_coord[9][32]: {int4 co, float4 cw} per (kk,pos), computed once
//    (arithmetic bit-identical to proven rounds).
//  - craw[2][32 pos][4 corners][256B] = 2 x 32 KB: corners(kk+1) DMAed at
//    iteration top (8 instrs/wave, 1 KB each; source pre-XOR-swizzled,
//    LDS dest linear per HW rule; read side XORs posl to undo).
//  - interp: lane (posl,kg) reads its 4 corners x 16B from craw (lgkm
//    only), interps into the r5/r6-PROVEN A-fragment mapping; MFMA +
//    epilogue are r6-k_gemm-verbatim (wave: pos-half = wv>>1, o-half = wv&1).
//  - DMA consumes ZERO VGPRs -> compiler cannot collapse this pipeline
//    (the r2-r6 failure mode: VGPR 60-108, prefetch always sunk to use).
// LDS 73 KB -> 2 blocks/CU. launch_bounds(256,2) = 256-VGPR budget.
// ---------------------------------------------------------------------------
__global__ __launch_bounds__(256, 2)
void k_main(const u16* __restrict__ xT, const float* __restrict__ offs,
            const u16* __restrict__ wT, const float* __restrict__ b_def,
            float* __restrict__ out) {
    __shared__ __align__(16) u16 s_craw[32768];   // 2 x 32 KB (u16 units)
    __shared__ __align__(16) u16 s_coord[4608];   // 288 entries x 32 B

    const int t = threadIdx.x, lane = t & 63, wv = t >> 6;   // wv 0..3
    const int posl = lane & 15, kg = lane >> 4;
    const int bid = blockIdx.x;
    const int b = bid & 7, rest = bid >> 3;
    const int h = rest >> 1, half = rest & 1;
    const int pos0 = half * 32;
    const char* xb = (const char*)xT + (size_t)b * (HW * CC * 2);

    // ---- coord table: 9 kk x 32 pos, exact proven arithmetic ----
    for (int e = t; e < 288; e += 256) {
        const int kk = e >> 5, pl = e & 31;
        const int pw = pos0 + pl;
        const float oy = offs[(b * NJ + 2 * kk) * HW + h * WW + pw];
        const float ox = offs[(b * NJ + 2 * kk + 1) * HW + h * WW + pw];
        const int ky = kk / 3, kx = kk - ky * 3;
        float py = (float)(h - 1 + ky) + oy;
        float px = (float)(pw - 1 + kx) + ox;
        float fy = floorf(py), fx = floorf(px);
        int iy0 = (int)fy, ix0 = (int)fx;
        float wy = py - fy, wx = px - fx;
        int iy1 = iy0 + 1, ix1 = ix0 + 1;
        float my0 = (iy0 >= 0 && iy0 < HH) ? 1.0f : 0.0f;
        float my1 = (iy1 >= 0 && iy1 < HH) ? 1.0f : 0.0f;
        float mx0 = (ix0 >= 0 && ix0 < WW) ? 1.0f : 0.0f;
        float mx1 = (ix1 >= 0 && ix1 < WW) ? 1.0f : 0.0f;
        int iy0c = min(max(iy0, 0), HH - 1), iy1c = min(max(iy1, 0), HH - 1);
        int ix0c = min(max(ix0, 0), WW - 1), ix1c = min(max(ix1, 0), WW - 1);
        float wy1 = 1.0f - wy, wx1 = 1.0f - wx;
        float4 cw = make_float4(my0 * mx0 * wy1 * wx1, my0 * mx1 * wy1 * wx,
                                my1 * mx0 * wy  * wx1, my1 * mx1 * wy  * wx);
        int4 co = make_int4((iy0c * WW + ix0c) << 8, (iy0c * WW + ix1c) << 8,
                            (iy1c * WW + ix0c) << 8, (iy1c * WW + ix1c) << 8);
        *(int4*)&s_coord[e * 16] = co;
        *(float4*)&s_coord[e * 16 + 8] = cw;
    }
    __syncthreads();

    // ---- async DMA: corners of kk kkn -> craw[buf]; 8 instrs/wave ----
    // instr i (pos_local=i, wave-uniform): lane l = corner (l>>4), slot
    // (l&15). Source pre-swizzled: fetch global slot (l&15)^(i&15); LDS
    // written linearly at base + l*16 (HW rule). Read side XORs posl.
    auto dma_kk = [&](int kkn, int buf) {
#pragma unroll
        for (int i2 = 0; i2 < 8; ++i2) {
            const int i = wv * 8 + i2;
            const int corner = lane >> 4;
            const int co_c = *(const int*)&s_coord[(kkn * 32 + i) * 16 + corner * 2];
            const int ssrc = ((lane & 15) ^ (i & 15)) * 16;
            const u16* dst = s_craw + buf * 16384 + i * 512;   // uniform base
            __builtin_amdgcn_global_load_lds(
                (const __attribute__((address_space(1))) u32*)(xb + co_c + ssrc),
                (__attribute__((address_space(3))) u32*)dst, 16, 0, 0);
        }
    };

    const int p0l = (wv >> 1) * 16;      // wave's pos_local base (0 or 16)
    const int oh = wv & 1;               // o-half
    const int mypl = p0l + posl;         // this lane's pos_local

    f32x4 acc[4];
#pragma unroll
    for (int ot = 0; ot < 4; ++ot) acc[ot] = (f32x4){0.f, 0.f, 0.f, 0.f};

    // ---- prolog: corners(0) ----
    dma_kk(0, 0);
    __syncthreads();                      // drains vmcnt(0) + barrier

#pragma unroll
    for (int kk = 0; kk < 9; ++kk) {
        const int cur = kk & 1;
        if (kk < 8) dma_kk(kk + 1, cur ^ 1);   // in flight across this iter

        // ---- interp: craw -> A-fragments (proven per-lane mapping) ----
        const float4 cw = *(const float4*)&s_coord[(kk * 32 + mypl) * 16 + 8];
        const u16* rowb = s_craw + cur * 16384 + mypl * 512;
        bf16x8 A[4];
#pragma unroll
        for (int ks = 0; ks < 4; ++ks) {
            const int slot = (((ks * 4 + kg) ^ posl)) * 8;    // undo swizzle
            uint4 c0 = *(const uint4*)&rowb[slot];            // (iy0,ix0)
            uint4 c1 = *(const uint4*)&rowb[128 + slot];      // (iy0,ix1)
            uint4 c2 = *(const uint4*)&rowb[256 + slot];      // (iy1,ix0)
            uint4 c3 = *(const uint4*)&rowb[384 + slot];      // (iy1,ix1)
            const u32* u00 = (const u32*)&c0;
            const u32* u01 = (const u32*)&c1;
            const u32* u10 = (const u32*)&c2;
            const u32* u11 = (const u32*)&c3;
            union { u32 d[4]; bf16x8 v; } pk;
#pragma unroll
            for (int i = 0; i < 4; ++i) {
                float s0 = cw.x * bflo(u00[i]) + cw.y * bflo(u01[i])
                         + cw.z * bflo(u10[i]) + cw.w * bflo(u11[i]);
                float s1 = cw.x * bfhi(u00[i]) + cw.y * bfhi(u01[i])
                         + cw.z * bfhi(u10[i]) + cw.w * bfhi(u11[i]);
                pk.d[i] = pk2bf(s0, s1);
            }
            A[ks] = pk.v;
        }

        // ---- GEMM (r6 k_gemm verbatim semantics) ----
        const u16* wkk = wT + kk * (OO * CC);
#pragma unroll
        for (int ks = 0; ks < 4; ++ks)
#pragma unroll
            for (int ot = 0; ot < 4; ++ot) {
                bf16x8 wfr = *(const bf16x8*)
                    &wkk[(oh * 64 + ot * 16 + posl) * CC + ks * 32 + kg * 8];
                acc[ot] = __builtin_amdgcn_mfma_f32_16x16x32_bf16(
                    A[ks], wfr, acc[ot], 0, 0, 0);
            }

        // ---- end of iter: corners(kk+1) landed across all waves ----
        if (kk < 8) __syncthreads();
    }

    // ---- epilogue (r6-proven): D col = o, row = pos = pos0+p0l+kg*4+r ----
    const int wbase = pos0 + p0l;
#pragma unroll
    for (int ot = 0; ot < 4; ++ot) {
        const int o = oh * 64 + ot * 16 + posl;
        const float bd = b_def[o];
        float4 res;
        res.x = acc[ot][0] + bd;
        res.y = acc[ot][1] + bd;
        res.z = acc[ot][2] + bd;
        res.w = acc[ot][3] + bd;
        *(float4*)&out[((b * OO + o) * HH + h) * WW + wbase + kg * 4] = res;
    }
}

extern "C" void kernel_launch(void* const* d_in, const int* in_sizes, int n_in,
                              void* d_out, int out_size, void* d_ws, size_t ws_size,
                              hipStream_t stream) {
    const float* x     = (const float*)d_in[0];
    const float* w_off = (const float*)d_in[1];
    const float* b_off = (const float*)d_in[2];
    const float* w_def = (const float*)d_in[3];
    const float* b_def = (const float*)d_in[4];
    float* out = (float*)d_out;

    float* offs = (float*)d_ws;                  // 8*18*4096 f32 = 2.36 MB
    u16*   xT   = (u16*)(offs + BB * NJ * HW);   // 8*4096*128    = 8.39 MB
    u16*   wT   = xT + (size_t)BB * HW * CC;     // 9*128*128     = 0.29 MB
    u16*   wA   = wT + 9 * OO * CC;              // 32*1152       = 0.07 MB

    k_pre <<<1088, 256, 0, stream>>>(x, xT, w_def, w_off, wT, wA);
    k_off <<< 512, 256, 0, stream>>>(xT, wA, b_off, offs);
    k_main<<<1024, 256, 0, stream>>>(xT, offs, wT, b_def, out);
}